// Round 10
// baseline (76.983 us; speedup 1.0000x reference)
//
#include <hip/hip_runtime.h>

typedef __attribute__((ext_vector_type(4))) float f32x4;
typedef __attribute__((ext_vector_type(2))) long long i64x2;

static constexpr int D = 256;
static constexpr float INV_T = 2.0f;                 // 1 / temperature(0.5)
static constexpr float KEXP2 = 2.8853900817779268f;  // 2*log2(e): exp(2x) = 2^(KEXP2*x)
static constexpr int TTILE = 64;                     // 8192 / 128
static constexpr int NBLK = TTILE * (TTILE + 1) / 2; // 2080 upper-triangle tiles
static constexpr int PBLK = 256;                     // persistent blocks (1/CU)
// zn fp8 paired-kk fragment layout (per 128-row tile = contiguous 32 KB):
//   byte = ti*32768 + rb*4096 + kkp*1024 + lane*16 + half*8 + e
//   where rb=(row>>4)&7, kkp=k>>6, half=(k>>5)&1, lane=((k>>3)&3)*16+(row&15), e=k&7
// Reader: ds_read_b128 at (rb*4+kkp)*1024 + lane*16 -> [even kk | odd kk] operands.

__device__ inline float fexp2(float x) {
#if __has_builtin(__builtin_amdgcn_exp2f)
    return __builtin_amdgcn_exp2f(x);
#else
    return exp2f(x);
#endif
}
// Direct global->LDS DMA (16B/lane). LDS dest = wave-uniform base + lane*16.
__device__ inline void gload_lds16(const void* g, void* l) {
    typedef __attribute__((address_space(3))) unsigned int lds_u32_t;
    typedef __attribute__((address_space(1))) const unsigned int glb_u32_t;
    __builtin_amdgcn_global_load_lds((glb_u32_t*)g, (lds_u32_t*)l, 16, 0, 0);
}
// 4 floats -> 4 packed OCP e4m3 bytes (RNE HW instr, bit-identical to MFMA input).
__device__ inline unsigned int cvt4_fp8(float a, float b, float c, float d) {
    int v = __builtin_amdgcn_cvt_pk_fp8_f32(a, b, 0, false);
    v = __builtin_amdgcn_cvt_pk_fp8_f32(c, d, v, true);
    return (unsigned int)v;
}

// Kernel 1: per pair i in [0,B): normalize rows i and i+B, quantize to fp8,
// scatter into paired-kk fragment layout; diag[i] = -exp(2*selfdot_fp8);
// positive-pair dot (fp8 values) -> per-block partial. No atomics.
__global__ void k_norm(const float* __restrict__ zi, const float* __restrict__ zj,
                       unsigned char* __restrict__ zn, float* __restrict__ diag,
                       float* __restrict__ pos_partial, int B) {
    __shared__ float red[4];
    const int lane = threadIdx.x & 63;
    const int wv = threadIdx.x >> 6;
    const int i = blockIdx.x * 4 + wv;       // pair index
    if (i < B) {
        float4 vi = reinterpret_cast<const float4*>(zi + (size_t)i * D)[lane];
        float4 vj = reinterpret_cast<const float4*>(zj + (size_t)i * D)[lane];
        float ssi = vi.x * vi.x + vi.y * vi.y + vi.z * vi.z + vi.w * vi.w;
        float ssj = vj.x * vj.x + vj.y * vj.y + vj.z * vj.z + vj.w * vj.w;
#pragma unroll
        for (int off = 32; off >= 1; off >>= 1) {
            ssi += __shfl_xor(ssi, off, 64);
            ssj += __shfl_xor(ssj, off, 64);
        }
        float rni = rsqrtf(ssi), rnj = rsqrtf(ssj);
        unsigned int pa = cvt4_fp8(vi.x * rni, vi.y * rni, vi.z * rni, vi.w * rni);
        unsigned int pb = cvt4_fp8(vj.x * rnj, vj.y * rnj, vj.z * rnj, vj.w * rnj);
        // decode quantized values (exact match with MFMA operands)
        float fa0 = __builtin_amdgcn_cvt_f32_fp8((int)pa, 0);
        float fa1 = __builtin_amdgcn_cvt_f32_fp8((int)pa, 1);
        float fa2 = __builtin_amdgcn_cvt_f32_fp8((int)pa, 2);
        float fa3 = __builtin_amdgcn_cvt_f32_fp8((int)pa, 3);
        float fb0 = __builtin_amdgcn_cvt_f32_fp8((int)pb, 0);
        float fb1 = __builtin_amdgcn_cvt_f32_fp8((int)pb, 1);
        float fb2 = __builtin_amdgcn_cvt_f32_fp8((int)pb, 2);
        float fb3 = __builtin_amdgcn_cvt_f32_fp8((int)pb, 3);
        float sdi = fa0 * fa0 + fa1 * fa1 + fa2 * fa2 + fa3 * fa3;
        float sdj = fb0 * fb0 + fb1 * fb1 + fb2 * fb2 + fb3 * fb3;
        float pd  = fa0 * fb0 + fa1 * fb1 + fa2 * fb2 + fa3 * fb3;
#pragma unroll
        for (int off = 32; off >= 1; off >>= 1) {
            sdi += __shfl_xor(sdi, off, 64);
            sdj += __shfl_xor(sdj, off, 64);
            pd  += __shfl_xor(pd, off, 64);
        }
        // scatter: lane pair (2m,2m+1) holds k=8m..8m+7 -> one 8B slot
        unsigned int qa = __shfl_xor(pa, 1, 64);
        unsigned int qb = __shfl_xor(pb, 1, 64);
        if ((lane & 1) == 0) {
            int m = lane >> 1;   // 0..31
            size_t base = (size_t)(m >> 3) * 1024 + (size_t)((m & 3) * 16) * 16
                        + (size_t)(((m >> 2) & 1)) * 8;
            size_t offA = (size_t)(i >> 4) * 4096 + base + (size_t)(i & 15) * 16;
            int ib = i + B;
            size_t offB = (size_t)(ib >> 4) * 4096 + base + (size_t)(ib & 15) * 16;
            *reinterpret_cast<unsigned long long*>(zn + offA) =
                ((unsigned long long)qa << 32) | pa;
            *reinterpret_cast<unsigned long long*>(zn + offB) =
                ((unsigned long long)qb << 32) | pb;
        }
        if (lane == 0) {
            diag[i]     = -fexp2(KEXP2 * sdi);
            diag[i + B] = -fexp2(KEXP2 * sdj);
            red[wv] = pd;
        }
    } else if (lane == 0) {
        red[wv] = 0.f;
    }
    __syncthreads();
    if (threadIdx.x == 0)
        pos_partial[blockIdx.x] = 2.0f * INV_T * (red[0] + red[1] + red[2] + red[3]);
}

// Kernel 2: PERSISTENT pipelined tiles. 256 blocks (1/CU) x 8 waves; each
// block grid-strides the 2080 upper-triangle 128x128 tiles. A+B fp8 panels
// (full K) double-buffered in LDS (128 KB): issue tile t+1's global_load_lds
// BEFORE computing tile t, so the L2 stage (~1.2k cyc) hides under compute
// (~1.6k cyc) and the barrier drain finds loads already landed (R8/R9 exposed
// the stage serially every tile -> MfmaUtil 10-14%).
__global__ __launch_bounds__(512, 2)
void k_main(const unsigned char* __restrict__ zn, float* __restrict__ P, int N) {
    __shared__ __align__(16) unsigned char buf[2][65536];
    __shared__ float rlds[4][128];
    __shared__ float clds[2][128];
    const int tid = threadIdx.x;
    const int lane = tid & 63, wv = tid >> 6;
    const int l15 = lane & 15, lhi = lane >> 4;
    const int wr = wv >> 2, wc = wv & 3;         // wave grid 2 x 4 (64x32 each)

    // wave wv stages 8 KB: wv<4 -> A-panel chunk wv, wv>=4 -> B-panel chunk wv-4
    auto stage = [&](int b, int ti_, int tj_) {
        const unsigned char* src = (wv < 4)
            ? zn + (size_t)ti_ * 32768 + (size_t)wv * 8192
            : zn + (size_t)tj_ * 32768 + (size_t)(wv - 4) * 8192;
        unsigned char* dst = &buf[b][(wv < 4) ? wv * 8192 : 32768 + (wv - 4) * 8192];
#pragma unroll
        for (int q = 0; q < 8; ++q)
            gload_lds16(src + q * 1024 + lane * 16, dst + q * 1024);
    };
    auto decode = [&](int t, int& ti_, int& tj_) {
        int a = 0, rem = t;
        while (rem >= TTILE - a) { rem -= TTILE - a; ++a; }
        ti_ = a; tj_ = a + rem;
    };

    int t = blockIdx.x;
    if (t >= NBLK) return;
    int ti, tj;
    decode(t, ti, tj);
    stage(0, ti, tj);
    __syncthreads();
    int cur = 0;

    for (;;) {
        const int tn = t + PBLK;
        const bool more = (tn < NBLK);
        int ti_n, tj_n;
        if (more) {                       // T14: next tile's DMA in flight
            decode(tn, ti_n, tj_n);
            stage(cur ^ 1, ti_n, tj_n);
        }

        // ---- compute tile (ti,tj) from buf[cur] ----
        f32x4 acc[4][2];
#pragma unroll
        for (int r = 0; r < 4; ++r)
#pragma unroll
            for (int c = 0; c < 2; ++c) acc[r][c] = (f32x4){0.f, 0.f, 0.f, 0.f};

        const i64x2* A  = reinterpret_cast<const i64x2*>(&buf[cur][0]);
        const i64x2* Bp = reinterpret_cast<const i64x2*>(&buf[cur][32768]);
#pragma unroll
        for (int kkp = 0; kkp < 4; ++kkp) {
            i64x2 a_[4], b_[2];
#pragma unroll
            for (int r = 0; r < 4; ++r)
                a_[r] = A[((wr * 4 + r) * 4 + kkp) * 64 + lane];
#pragma unroll
            for (int c = 0; c < 2; ++c)
                b_[c] = Bp[((wc * 2 + c) * 4 + kkp) * 64 + lane];
#pragma unroll
            for (int r = 0; r < 4; ++r)
#pragma unroll
                for (int c = 0; c < 2; ++c) {
                    acc[r][c] = __builtin_amdgcn_mfma_f32_16x16x32_fp8_fp8(
                        a_[r].x, b_[c].x, acc[r][c], 0, 0, 0);
                    acc[r][c] = __builtin_amdgcn_mfma_f32_16x16x32_fp8_fp8(
                        a_[r].y, b_[c].y, acc[r][c], 0, 0, 0);
                }
        }

        // ---- tail: e = exp(2*sim); per-wave row/col partials ----
        // row = wr*64 + r*16 + lhi*4 + q ; col = wc*32 + c*16 + l15
        float cs[2] = {0.f, 0.f};
#pragma unroll
        for (int r = 0; r < 4; ++r) {
            float rsq[4] = {0.f, 0.f, 0.f, 0.f};
#pragma unroll
            for (int c = 0; c < 2; ++c)
#pragma unroll
                for (int q = 0; q < 4; ++q) {
                    float e = fexp2(KEXP2 * acc[r][c][q]);
                    rsq[q] += e;
                    cs[c] += e;
                }
#pragma unroll
            for (int q = 0; q < 4; ++q) {
                float v = rsq[q];
                v += __shfl_xor(v, 1, 64);
                v += __shfl_xor(v, 2, 64);
                v += __shfl_xor(v, 4, 64);
                v += __shfl_xor(v, 8, 64);
                if (l15 == 0)
                    rlds[wc][wr * 64 + r * 16 + lhi * 4 + q] = v;
            }
        }
#pragma unroll
        for (int c = 0; c < 2; ++c) {
            float v = cs[c];
            v += __shfl_xor(v, 16, 64);
            v += __shfl_xor(v, 32, 64);
            if (lhi == 0)
                clds[wr][wc * 32 + c * 16 + l15] = v;
        }
        __syncthreads();   // partials visible (also drains stage DMA - landed)

        if (tid < 128) {
            P[(size_t)tj * N + ti * 128 + tid] =
                rlds[0][tid] + rlds[1][tid] + rlds[2][tid] + rlds[3][tid];
        } else if (tid < 256 && ti != tj) {
            int c = tid - 128;
            P[(size_t)ti * N + tj * 128 + c] = clds[0][c] + clds[1][c];
        }
        __syncthreads();   // combine reads done; buffers swappable

        if (!more) break;
        t = tn; ti = ti_n; tj = tj_n; cur ^= 1;
    }
}

// Kernel 3: per row, sum the 64 partials + diag term, take log; block partial.
__global__ void k_lse(const float* __restrict__ P, const float* __restrict__ diag,
                      float* __restrict__ part, int N) {
    __shared__ float red[4];
    const int lane = threadIdx.x & 63, wv = threadIdx.x >> 6;
    const int row = blockIdx.x * 256 + threadIdx.x;
    float s = diag[row];
#pragma unroll
    for (int k = 0; k < TTILE; ++k) s += P[(size_t)k * N + row];
    float local = __logf(s);
#pragma unroll
    for (int off = 32; off >= 1; off >>= 1) local += __shfl_xor(local, off, 64);
    if (lane == 0) red[wv] = local;
    __syncthreads();
    if (threadIdx.x == 0)
        part[blockIdx.x] = red[0] + red[1] + red[2] + red[3];
}

// Kernel 4: loss = (sum part - sum pos_partial) / N
__global__ void k_final(const float* __restrict__ part, int n_part,
                        const float* __restrict__ pos_partial, int n_pos,
                        float* __restrict__ out, int N) {
    __shared__ float red[16];
    int lane = threadIdx.x & 63, wv = threadIdx.x >> 6;
    float local = 0.f;
    for (int i = threadIdx.x; i < n_part; i += 1024) local += part[i];
    for (int i = threadIdx.x; i < n_pos; i += 1024) local -= pos_partial[i];
#pragma unroll
    for (int off = 32; off >= 1; off >>= 1) local += __shfl_xor(local, off, 64);
    if (lane == 0) red[wv] = local;
    __syncthreads();
    if (threadIdx.x == 0) {
        float t = 0.f;
#pragma unroll
        for (int w = 0; w < 16; ++w) t += red[w];
        out[0] = t / (float)N;
    }
}

extern "C" void kernel_launch(void* const* d_in, const int* in_sizes, int n_in,
                              void* d_out, int out_size, void* d_ws, size_t ws_size,
                              hipStream_t stream) {
    const float* zi = (const float*)d_in[0];
    const float* zj = (const float*)d_in[1];
    const int B = in_sizes[0] / D;   // 4096
    const int N = 2 * B;             // 8192

    char* ws = (char*)d_ws;
    unsigned char* zn = (unsigned char*)ws;              // N*D fp8 = 2 MB
    float* diag = (float*)(ws + (size_t)N * D);          // N f32 = 32 KB
    float* pos_partial = diag + N;                       // B/4 = 1024 f32
    float* part = pos_partial + 1024;                    // 32 f32
    float* P = part + 64;                                // 64*N f32 = 2 MB

    float* out = (float*)d_out;

    const int npb = B / 4;  // 1024 k_norm blocks == pos partials
    hipLaunchKernelGGL(k_norm, dim3(npb), dim3(256), 0, stream, zi, zj, zn, diag, pos_partial, B);
    hipLaunchKernelGGL(k_main, dim3(PBLK), dim3(512), 0, stream, zn, P, N);
    hipLaunchKernelGGL(k_lse, dim3(N / 256), dim3(256), 0, stream, P, diag, part, N);
    hipLaunchKernelGGL(k_final, dim3(1), dim3(1024), 0, stream, part, N / 256, pos_partial, npb, out, N);
}

// Round 11
// 40.540 us; speedup vs baseline: 1.8989x; 1.8989x over previous
//
#include <hip/hip_runtime.h>

typedef __attribute__((ext_vector_type(4))) float f32x4;
typedef __attribute__((ext_vector_type(2))) long long i64x2;

static constexpr int D = 256;
static constexpr float INV_T = 2.0f;                 // 1 / temperature(0.5)
static constexpr float KEXP2 = 2.8853900817779268f;  // 2*log2(e): exp(2x) = 2^(KEXP2*x)
static constexpr int TTILE = 64;                     // 8192 / 128
static constexpr int NBLK = TTILE * (TTILE + 1) / 2; // 2080 upper-triangle tiles
static constexpr int NPLANE = 2 * TTILE;             // 128 partial planes
// zn fp8 paired-kk fragment layout (per 128-row tile = contiguous 32 KB):
//   byte = ti*32768 + rb*4096 + kkp*1024 + lane*16 + half*8 + e
//   rb=(row>>4)&7, kkp=k>>6, half=(k>>5)&1, lane=((k>>3)&3)*16+(row&15), e=k&7
// Reader: 16B load at (rb*4+kkp)*1024 + lane*16 -> [kk even | kk odd] operands.
// (Layout verified end-to-end in R10: absmax = 0.)

__device__ inline float fexp2(float x) {
#if __has_builtin(__builtin_amdgcn_exp2f)
    return __builtin_amdgcn_exp2f(x);
#else
    return exp2f(x);
#endif
}
// 4 floats -> 4 packed OCP e4m3 bytes (RNE HW instr, bit-identical to MFMA input).
__device__ inline unsigned int cvt4_fp8(float a, float b, float c, float d) {
    int v = __builtin_amdgcn_cvt_pk_fp8_f32(a, b, 0, false);
    v = __builtin_amdgcn_cvt_pk_fp8_f32(c, d, v, true);
    return (unsigned int)v;
}

// Kernel 1 (unchanged from R10, verified): normalize pair rows to fp8 in the
// fragment layout; diag[i] = -exp(2*selfdot_fp8); pos dot -> block partial.
__global__ void k_norm(const float* __restrict__ zi, const float* __restrict__ zj,
                       unsigned char* __restrict__ zn, float* __restrict__ diag,
                       float* __restrict__ pos_partial, int B) {
    __shared__ float red[4];
    const int lane = threadIdx.x & 63;
    const int wv = threadIdx.x >> 6;
    const int i = blockIdx.x * 4 + wv;       // pair index
    if (i < B) {
        float4 vi = reinterpret_cast<const float4*>(zi + (size_t)i * D)[lane];
        float4 vj = reinterpret_cast<const float4*>(zj + (size_t)i * D)[lane];
        float ssi = vi.x * vi.x + vi.y * vi.y + vi.z * vi.z + vi.w * vi.w;
        float ssj = vj.x * vj.x + vj.y * vj.y + vj.z * vj.z + vj.w * vj.w;
#pragma unroll
        for (int off = 32; off >= 1; off >>= 1) {
            ssi += __shfl_xor(ssi, off, 64);
            ssj += __shfl_xor(ssj, off, 64);
        }
        float rni = rsqrtf(ssi), rnj = rsqrtf(ssj);
        unsigned int pa = cvt4_fp8(vi.x * rni, vi.y * rni, vi.z * rni, vi.w * rni);
        unsigned int pb = cvt4_fp8(vj.x * rnj, vj.y * rnj, vj.z * rnj, vj.w * rnj);
        float fa0 = __builtin_amdgcn_cvt_f32_fp8((int)pa, 0);
        float fa1 = __builtin_amdgcn_cvt_f32_fp8((int)pa, 1);
        float fa2 = __builtin_amdgcn_cvt_f32_fp8((int)pa, 2);
        float fa3 = __builtin_amdgcn_cvt_f32_fp8((int)pa, 3);
        float fb0 = __builtin_amdgcn_cvt_f32_fp8((int)pb, 0);
        float fb1 = __builtin_amdgcn_cvt_f32_fp8((int)pb, 1);
        float fb2 = __builtin_amdgcn_cvt_f32_fp8((int)pb, 2);
        float fb3 = __builtin_amdgcn_cvt_f32_fp8((int)pb, 3);
        float sdi = fa0 * fa0 + fa1 * fa1 + fa2 * fa2 + fa3 * fa3;
        float sdj = fb0 * fb0 + fb1 * fb1 + fb2 * fb2 + fb3 * fb3;
        float pd  = fa0 * fb0 + fa1 * fb1 + fa2 * fb2 + fa3 * fb3;
#pragma unroll
        for (int off = 32; off >= 1; off >>= 1) {
            sdi += __shfl_xor(sdi, off, 64);
            sdj += __shfl_xor(sdj, off, 64);
            pd  += __shfl_xor(pd, off, 64);
        }
        unsigned int qa = __shfl_xor(pa, 1, 64);
        unsigned int qb = __shfl_xor(pb, 1, 64);
        if ((lane & 1) == 0) {
            int m = lane >> 1;   // 0..31 -> k = 8m..8m+7
            size_t base = (size_t)(m >> 3) * 1024 + (size_t)((m & 3) * 16) * 16
                        + (size_t)(((m >> 2) & 1)) * 8;
            size_t offA = (size_t)(i >> 4) * 4096 + base + (size_t)(i & 15) * 16;
            int ib = i + B;
            size_t offB = (size_t)(ib >> 4) * 4096 + base + (size_t)(ib & 15) * 16;
            *reinterpret_cast<unsigned long long*>(zn + offA) =
                ((unsigned long long)qa << 32) | pa;
            *reinterpret_cast<unsigned long long*>(zn + offB) =
                ((unsigned long long)qb << 32) | pb;
        }
        if (lane == 0) {
            diag[i]     = -fexp2(KEXP2 * sdi);
            diag[i + B] = -fexp2(KEXP2 * sdj);
            red[wv] = pd;
        }
    } else if (lane == 0) {
        red[wv] = 0.f;
    }
    __syncthreads();
    if (threadIdx.x == 0)
        pos_partial[blockIdx.x] = 2.0f * INV_T * (red[0] + red[1] + red[2] + red[3]);
}

// Kernel 2: BARRIER-FREE, LDS-FREE upper-triangle tiles. zn (2 MB fp8) is
// L2-resident on every XCD -> LDS staging was pure overhead that barrier
// drains kept exposing (R8-R10 all stuck at MfmaUtil 10-14%). Each wave:
// fragments global->VGPR directly, 128 fp8 MFMAs for its 64x64 quadrant,
// exp tail, partial sums to a wave-private P plane (no atomics, no syncs).
// Plane coverage (exactly-once): plane 2a+s gets rows t*128 from row-sums of
// blocks (t,a) t<=a (wave wc==s) and from col-sums of blocks (a,t) t>a
// (wave wr==s, skipped on diag).
__global__ __launch_bounds__(256, 2)
void k_main(const unsigned char* __restrict__ zn, float* __restrict__ P, int N) {
    const int tid = threadIdx.x;
    const int lane = tid & 63, wv = tid >> 6;
    const int l15 = lane & 15, lhi = lane >> 4;
    const int wr = wv >> 1, wc = wv & 1;         // wave grid 2 x 2, 64x64 each

    // XCD-aware bijective swizzle (NBLK = 2080 = 8 * 260)
    const int bid = (int)blockIdx.x;
    const int swz = (bid & 7) * (NBLK / 8) + (bid >> 3);
    int ti = 0, rem = swz;
    while (rem >= TTILE - ti) { rem -= TTILE - ti; ++ti; }
    const int tj = ti + rem;

    const i64x2* Ap = reinterpret_cast<const i64x2*>(zn + (size_t)ti * 32768);
    const i64x2* Bp = reinterpret_cast<const i64x2*>(zn + (size_t)tj * 32768);

    f32x4 acc[4][4];
#pragma unroll
    for (int r = 0; r < 4; ++r)
#pragma unroll
        for (int c = 0; c < 4; ++c) acc[r][c] = (f32x4){0.f, 0.f, 0.f, 0.f};

#pragma unroll
    for (int kkp = 0; kkp < 4; ++kkp) {
        i64x2 a_[4], b_[4];
#pragma unroll
        for (int r = 0; r < 4; ++r)
            a_[r] = Ap[((wr * 4 + r) * 4 + kkp) * 64 + lane];
#pragma unroll
        for (int c = 0; c < 4; ++c)
            b_[c] = Bp[((wc * 4 + c) * 4 + kkp) * 64 + lane];
#pragma unroll
        for (int r = 0; r < 4; ++r)
#pragma unroll
            for (int c = 0; c < 4; ++c) {
                acc[r][c] = __builtin_amdgcn_mfma_f32_16x16x32_fp8_fp8(
                    a_[r].x, b_[c].x, acc[r][c], 0, 0, 0);
                acc[r][c] = __builtin_amdgcn_mfma_f32_16x16x32_fp8_fp8(
                    a_[r].y, b_[c].y, acc[r][c], 0, 0, 0);
            }
    }

    // tail: e = exp(2*sim); row-sums -> plane 2*tj+wc; col-sums -> plane
    // 2*ti+wr (off-diag only). row = wr*64+r*16+lhi*4+q, col = wc*64+c*16+l15.
    float cs[4] = {0.f, 0.f, 0.f, 0.f};
#pragma unroll
    for (int r = 0; r < 4; ++r) {
        float rq0 = 0.f, rq1 = 0.f, rq2 = 0.f, rq3 = 0.f;
#pragma unroll
        for (int c = 0; c < 4; ++c) {
            float e0 = fexp2(KEXP2 * acc[r][c][0]);
            float e1 = fexp2(KEXP2 * acc[r][c][1]);
            float e2 = fexp2(KEXP2 * acc[r][c][2]);
            float e3 = fexp2(KEXP2 * acc[r][c][3]);
            rq0 += e0; rq1 += e1; rq2 += e2; rq3 += e3;
            cs[c] += e0 + e1 + e2 + e3;
        }
#pragma unroll
        for (int off = 1; off <= 8; off <<= 1) {
            rq0 += __shfl_xor(rq0, off, 64);
            rq1 += __shfl_xor(rq1, off, 64);
            rq2 += __shfl_xor(rq2, off, 64);
            rq3 += __shfl_xor(rq3, off, 64);
        }
        if (l15 == 0) {
            f32x4 out = (f32x4){rq0, rq1, rq2, rq3};
            *reinterpret_cast<f32x4*>(
                P + (size_t)(2 * tj + wc) * N + ti * 128 + wr * 64 + r * 16 + lhi * 4) = out;
        }
    }
    if (ti != tj) {
#pragma unroll
        for (int c = 0; c < 4; ++c) {
            float v = cs[c];
            v += __shfl_xor(v, 16, 64);
            v += __shfl_xor(v, 32, 64);
            if (lhi == 0)
                P[(size_t)(2 * ti + wr) * N + tj * 128 + wc * 64 + c * 16 + l15] = v;
        }
    }
}

// Kernel 3: per row, sum the 128 plane partials + diag term, log; block partial.
__global__ void k_lse(const float* __restrict__ P, const float* __restrict__ diag,
                      float* __restrict__ part, int N) {
    __shared__ float red[4];
    const int lane = threadIdx.x & 63, wv = threadIdx.x >> 6;
    const int row = blockIdx.x * 256 + threadIdx.x;
    float s = diag[row];
#pragma unroll 8
    for (int k = 0; k < NPLANE; ++k) s += P[(size_t)k * N + row];
    float local = __logf(s);
#pragma unroll
    for (int off = 32; off >= 1; off >>= 1) local += __shfl_xor(local, off, 64);
    if (lane == 0) red[wv] = local;
    __syncthreads();
    if (threadIdx.x == 0)
        part[blockIdx.x] = red[0] + red[1] + red[2] + red[3];
}

// Kernel 4: loss = (sum part - sum pos_partial) / N
__global__ void k_final(const float* __restrict__ part, int n_part,
                        const float* __restrict__ pos_partial, int n_pos,
                        float* __restrict__ out, int N) {
    __shared__ float red[16];
    int lane = threadIdx.x & 63, wv = threadIdx.x >> 6;
    float local = 0.f;
    for (int i = threadIdx.x; i < n_part; i += 1024) local += part[i];
    for (int i = threadIdx.x; i < n_pos; i += 1024) local -= pos_partial[i];
#pragma unroll
    for (int off = 32; off >= 1; off >>= 1) local += __shfl_xor(local, off, 64);
    if (lane == 0) red[wv] = local;
    __syncthreads();
    if (threadIdx.x == 0) {
        float t = 0.f;
#pragma unroll
        for (int w = 0; w < 16; ++w) t += red[w];
        out[0] = t / (float)N;
    }
}

extern "C" void kernel_launch(void* const* d_in, const int* in_sizes, int n_in,
                              void* d_out, int out_size, void* d_ws, size_t ws_size,
                              hipStream_t stream) {
    const float* zi = (const float*)d_in[0];
    const float* zj = (const float*)d_in[1];
    const int B = in_sizes[0] / D;   // 4096
    const int N = 2 * B;             // 8192

    char* ws = (char*)d_ws;
    unsigned char* zn = (unsigned char*)ws;              // N*D fp8 = 2 MB
    float* diag = (float*)(ws + (size_t)N * D);          // N f32 = 32 KB
    float* pos_partial = diag + N;                       // B/4 = 1024 f32
    float* part = pos_partial + 1024;                    // 32 f32
    float* P = part + 64;                                // 128*N f32 = 4 MB

    float* out = (float*)d_out;

    const int npb = B / 4;  // 1024 k_norm blocks == pos partials
    hipLaunchKernelGGL(k_norm, dim3(npb), dim3(256), 0, stream, zi, zj, zn, diag, pos_partial, B);
    hipLaunchKernelGGL(k_main, dim3(NBLK), dim3(256), 0, stream, zn, P, N);
    hipLaunchKernelGGL(k_lse, dim3(N / 256), dim3(256), 0, stream, P, diag, part, N);
    hipLaunchKernelGGL(k_final, dim3(1), dim3(1024), 0, stream, part, N / 256, pos_partial, npb, out, N);
}